// Round 6
// baseline (3435.144 us; speedup 1.0000x reference)
//
#include <hip/hip_runtime.h>
#include <hip/hip_bf16.h>

// Problem dims
#define B_   64
#define S_   256
#define E_   512
#define H_   1024
#define D_   512
#define C_   2
#define G4   4096   // 4*H
#define NB   128    // blocks in persistent recurrence

typedef __attribute__((ext_vector_type(8))) short short8;   // 8 bf16 (4 VGPRs)
typedef __attribute__((ext_vector_type(4))) float f32x4;
typedef __attribute__((ext_vector_type(4))) unsigned int u32x4;  // asm-safe 16B

__device__ __forceinline__ float bf2f(unsigned short u) {
    unsigned int x = ((unsigned int)u) << 16;
    return __uint_as_float(x);
}
__device__ __forceinline__ unsigned short f2bf(float f) {
    unsigned int x = __float_as_uint(f);
    unsigned int r = (x + 0x7fffu + ((x >> 16) & 1u)) >> 16;
    return (unsigned short)r;
}

// ---------------------------------------------------------------------------
// Kernel D: detect fp32 (flag=1) vs bf16 (flag=0) float inputs (probe emb).
__global__ void detect_kernel(const unsigned short* __restrict__ emb_u,
                              int* __restrict__ flag)
{
    __shared__ int cnt;
    if (threadIdx.x == 0) cnt = 0;
    __syncthreads();
    int bad = 0;
#pragma unroll
    for (int i = 0; i < 8; ++i) {
        unsigned short u = emb_u[threadIdx.x * 8 + i];
        float a = fabsf(bf2f(u));
        if (!(a < 4.0f)) bad = 1;
        else if (a != 0.0f && a < 1e-20f) bad = 1;
    }
    if (bad) atomicAdd(&cnt, 1);
    __syncthreads();
    if (threadIdx.x == 0) *flag = (cnt > 16) ? 1 : 0;
}

// ---------------------------------------------------------------------------
// Workspace float offsets
#define OFF_WFX   0L          // 2097152  (Wx rows 0..511, fp32 [k][n])
#define OFF_WB    2097152L    // 4194304 floats = 8.4M ushort: MFMA B-frags
#define OFF_BIAS  6291456L    // 4096
#define OFF_WD    6295552L    // 524288
#define OFF_DB    6819840L    // 512
#define OFF_WP    6820352L    // 1024
#define OFF_PB    6821376L    // 16 (2 used)
#define OFF_FH    6821392L    // 65536
#define OFF_DEN   6886928L    // 32768
#define OFF_HH    6919696L    // 131072 floats = 4 ushort bufs of 65536:
                              //   A-frag-order h: hiA, loA, hiB, loB
#define OFF_BAR   7050768L    // 512 uints: ctr@0, go@32+w*32 (w=0..7), flag@400
#define OFF_XPROJ 7051280L    // 67108864

// Kernel P: convert/relayout weights (bf16 hi/lo MFMA B-frag order),
// zero fhT, t=0 h buffers, ctr/go flags (bar uints [0,384)).
#define PREP_TOTAL 6952834
__global__ void prep_kernel(const void* __restrict__ lk,
                            const void* __restrict__ lb,
                            const void* __restrict__ dw,
                            const void* __restrict__ dbm,
                            const void* __restrict__ pw,
                            const void* __restrict__ pbm,
                            const int* __restrict__ flag,
                            float* __restrict__ w)
{
    const bool f32 = (*flag != 0);
    long i = (long)blockIdx.x * 256 + threadIdx.x;
    if (i >= PREP_TOTAL) return;
#define CV(p, j) (f32 ? ((const float*)(p))[j] : bf2f(((const unsigned short*)(p))[j]))
    if (i < 2097152) { w[OFF_WFX + i] = CV(lk, i); return; }  i -= 2097152;
    if (i < 4194304) {
        // B-frag relayout (per 4-j group bk4): cols c=g*4+jj (n = g*1024 + bk4*4+jj).
        // lane l holds B[k = ks*32 + (l>>4)*8 + j][c = l&15], j=0..7.
        int j  = (int)(i & 7);
        int l  = (int)((i >> 3) & 63);
        int ks = (int)((i >> 9) & 31);
        int bk = (int)(i >> 14);
        int c  = l & 15, q = l >> 4;
        int k  = ks * 32 + q * 8 + j;
        int g  = c >> 2, jj = c & 3;
        long src = (long)(512 + k) * G4 + g * H_ + bk * 4 + jj;
        float v = CV(lk, src);
        unsigned short hi = f2bf(v);
        unsigned short lo = f2bf(v - bf2f(hi));
        unsigned short* WBu = (unsigned short*)(w + OFF_WB);
        long base = ((long)(bk * 32 + ks) * 2) * 512 + l * 8 + j;
        WBu[base]       = hi;   // term 0
        WBu[base + 512] = lo;   // term 1
        return;
    }  i -= 4194304;
    if (i < 4096)    { w[OFF_BIAS + i] = CV(lb, i);  return; }  i -= 4096;
    if (i < 524288)  { w[OFF_WD + i]   = CV(dw, i);  return; }  i -= 524288;
    if (i < 512)     { w[OFF_DB + i]   = CV(dbm, i); return; }  i -= 512;
    if (i < 1024)    { w[OFF_WP + i]   = CV(pw, i);  return; }  i -= 1024;
    if (i < 2)       { w[OFF_PB + i]   = CV(pbm, i); return; }  i -= 2;
    if (i < 65536)   { w[OFF_FH + i] = 0.f; return; }  i -= 65536;
    if (i < 65536)   { ((unsigned int*)(w + OFF_HH))[i] = 0u; return; }  i -= 65536;
    if (i < 384)     { ((unsigned int*)(w + OFF_BAR))[i] = 0u; return; }
#undef CV
}

// ---------------------------------------------------------------------------
// Kernel A: xprojT[t][n][b] = sum_e emb[X[b,t]][e] * Wfx[e][n] + bias[n]
__global__ __launch_bounds__(256) void xproj_kernel(
    const int* __restrict__ X,
    const void* __restrict__ emb,
    const int* __restrict__ flag,
    const float* __restrict__ Wfx,
    const float* __restrict__ biasf,
    float* __restrict__ xprojT)
{
    const int t    = blockIdx.y;
    const int cb   = blockIdx.x;
    const int tid  = threadIdx.x;
    const int lane = tid & 63;
    const int wv   = __builtin_amdgcn_readfirstlane(tid >> 6);
    const bool f32 = (*flag != 0);

    __shared__ float embT[128 * 64];
    __shared__ int   rowid[64];

    if (tid < 64) rowid[tid] = X[tid * S_ + t];
    __syncthreads();

    const int n0 = cb * 64 + wv * 16;
    float acc[16];
#pragma unroll
    for (int c = 0; c < 16; ++c) acc[c] = biasf[n0 + c];

    const long myrow = (long)rowid[lane] * E_;

    for (int kc = 0; kc < 4; ++kc) {
        const int k0 = kc * 128;
        if (f32) {
            const float4* src = (const float4*)((const float*)emb + myrow + k0 + wv * 32);
#pragma unroll
            for (int u = 0; u < 8; ++u) {
                float4 v = src[u];
                int kl = wv * 32 + u * 4;
                embT[(kl + 0) * 64 + lane] = v.x;
                embT[(kl + 1) * 64 + lane] = v.y;
                embT[(kl + 2) * 64 + lane] = v.z;
                embT[(kl + 3) * 64 + lane] = v.w;
            }
        } else {
            const uint4* src = (const uint4*)((const unsigned short*)emb + myrow + k0 + wv * 32);
#pragma unroll
            for (int u = 0; u < 4; ++u) {
                uint4 v = src[u];
                int kl = wv * 32 + u * 8;
                embT[(kl + 0) * 64 + lane] = bf2f((unsigned short)(v.x & 0xffff));
                embT[(kl + 1) * 64 + lane] = bf2f((unsigned short)(v.x >> 16));
                embT[(kl + 2) * 64 + lane] = bf2f((unsigned short)(v.y & 0xffff));
                embT[(kl + 3) * 64 + lane] = bf2f((unsigned short)(v.y >> 16));
                embT[(kl + 4) * 64 + lane] = bf2f((unsigned short)(v.z & 0xffff));
                embT[(kl + 5) * 64 + lane] = bf2f((unsigned short)(v.z >> 16));
                embT[(kl + 6) * 64 + lane] = bf2f((unsigned short)(v.w & 0xffff));
                embT[(kl + 7) * 64 + lane] = bf2f((unsigned short)(v.w >> 16));
            }
        }
        __syncthreads();

        const float* wbase = Wfx + (long)k0 * G4 + n0;
#pragma unroll 2
        for (int k = 0; k < 128; ++k) {
            float hv = embT[k * 64 + lane];
            const float* wr = wbase + (long)k * G4;
#pragma unroll
            for (int c = 0; c < 16; ++c) acc[c] += wr[c] * hv;
        }
        __syncthreads();
    }

    float* dst = xprojT + ((long)t * G4 + n0) * 64 + lane;
#pragma unroll
    for (int c = 0; c < 16; ++c) dst[c * 64] = acc[c];
}

// ---------------------------------------------------------------------------
// Persistent MFMA LSTM recurrence. 128 blocks x 512 thr (8 waves).
// Block bk owns h-dims j = bk*8..bk*8+7 -> 32 gate cols (two 16-col tiles).
// Waves = 4 m-tiles x 2 k-halves. Weights LDS-resident (128 KB).
//
// FENCELESS LLC protocol (rounds 2-5, verified): h moves via L1/L2-bypassing
// (sc0 sc1) accesses through the coherent LLC; release = per-wave vmcnt(0)
// drain of h stores before __syncthreads; acquire = bypassing loads. No
// cache-maintenance walks. Double-buffered h bounds skew to <=1 step.
//
// NEW this round (barrier-chain collapse):
//  * atomicAdd-last-arriver: after S3, tid 0 fetch_adds a single agent-scope
//    counter; the block observing old == 128*(t+1)-1 IS the barrier and
//    broadcasts go = t+1 to 8 replicated cache lines (one per wave index).
//    Removes the leader-detect hop of the round-5 tree (1 RMW RTT replaces
//    store -> poll-detect -> store).
//  * Per-wave go poll, NO closing __syncthreads: each wave polls its own go
//    line (64 lanes same addr = 1 coalesced request/iter) and proceeds
//    straight to its h loads. Cross-wave LDS hazards stay protected by
//    S1/S2/S3 (all cross-wave reads complete before S3; next-step writes
//    happen after each wave's own next S1).
//  * Poll path carries ZERO outstanding VMEM: xproj loads are issued inside
//    the step right after the h loads; vmcnt(4) starts MFMA when h arrives
//    while xproj drains under MFMA/S1. Release drain waits only on h-store
//    acks; poll iterations are pure LLC RTT.
__global__ __launch_bounds__(512, 2) void lstm_persistent(
    unsigned short* __restrict__ hU,     // hiA | loA | hiB | loB (65536 each)
    float* __restrict__ fhT,
    const unsigned short* __restrict__ WBg,
    const float* __restrict__ xprojT,
    const int* __restrict__ seqlen, unsigned int* __restrict__ done)
{
    const int tid  = threadIdx.x;
    const int lane = tid & 63;
    const int wv   = __builtin_amdgcn_readfirstlane(tid >> 6);  // 0..7
    const int bk   = blockIdx.x;        // 0..127
    const int mt   = wv & 3;            // m-tile (batch rows mt*16..+15)
    const int kh   = wv >> 2;           // k-half (ks in [kh*16, kh*16+16))

    __shared__ unsigned short WBl[65536];   // 128 KB B-frags (2 tiles)
    __shared__ float gates[2][64][33];      // [kh][m][tile*16+c] partials
    __shared__ float cTl[512];              // [jj][b] cell state
    __shared__ unsigned short hEx[2][512];  // [hi/lo][jj*64+b] exchange

    // stage weight frags (once) + init c
    {
        const uint4* src = (const uint4*)(WBg + (long)bk * 65536);
        uint4* dst = (uint4*)WBl;
#pragma unroll
        for (int u = 0; u < 16; ++u) dst[tid + u * 512] = src[tid + u * 512];
        cTl[tid] = 0.f;
    }
    __syncthreads();

    const int myseq = seqlen[lane];
    const int q = lane >> 4, c = lane & 15;
    const int jj = wv;                  // pointwise j owner: j = bk*8 + jj

    unsigned short* hiA = hU;
    unsigned short* loA = hU + 65536;
    unsigned short* hiB = hU + 131072;
    unsigned short* loB = hU + 196608;
    unsigned short *curHi = hiA, *curLo = loA, *nxtHi = hiB, *nxtLo = loB;

    // Packed 16B h-store role: 128 threads (sel = hi/lo, bb = batch) each
    // store one 16B vec = j-pairs 0..3 for (bb, sel).  Dword index:
    //   (bk>>2)*1024 + (bb>>4)*256 + (bk&3)*64 + (bb&15)*4   (16B aligned)
    const int sel = tid >> 6;           // valid for tid<128: 0=hi, 1=lo
    const int bb  = tid & 63;
    const long widx = (long)(bk >> 2) * 1024 + (bb >> 4) * 256
                    + (bk & 3) * 64 + (bb & 15) * 4;

    const long xoff = (long)(bk * 8 + jj);

    for (int t = 0; t < S_; ++t) {
        // ---- A-frag loads: m-tile mt, k-half kh; 32 x 16B, LLC-coherent ----
        const unsigned short* hiP = curHi + ((long)mt * 64 + lane) * 8;
        const unsigned short* loP = curLo + ((long)mt * 64 + lane) * 8;
        const int ks0 = kh * 16;

        u32x4 hb[16], lbv[16];
#pragma unroll
        for (int u = 0; u < 16; ++u) {
            asm volatile("global_load_dwordx4 %0, %1, off sc0 sc1"
                         : "=v"(hb[u])
                         : "v"(hiP + (long)(ks0 + u) * 2048) : "memory");
            asm volatile("global_load_dwordx4 %0, %1, off sc0 sc1"
                         : "=v"(lbv[u])
                         : "v"(loP + (long)(ks0 + u) * 2048) : "memory");
        }
        // xproj loads issued AFTER the h loads (drained by S1 under MFMA)
        float xq0, xq1, xq2, xq3;
        {
            const long xb = (long)t * G4 + xoff;
            const float* x0 = xprojT + (xb + 0 * H_) * 64 + lane;
            const float* x1 = xprojT + (xb + 1 * H_) * 64 + lane;
            const float* x2 = xprojT + (xb + 2 * H_) * 64 + lane;
            const float* x3 = xprojT + (xb + 3 * H_) * 64 + lane;
            asm volatile("global_load_dword %0, %1, off" : "=v"(xq0) : "v"(x0) : "memory");
            asm volatile("global_load_dword %0, %1, off" : "=v"(xq1) : "v"(x1) : "memory");
            asm volatile("global_load_dword %0, %1, off" : "=v"(xq2) : "v"(x2) : "memory");
            asm volatile("global_load_dword %0, %1, off" : "=v"(xq3) : "v"(x3) : "memory");
        }
        // wait for the 32 h loads only (4 xproj still outstanding)
        asm volatile("s_waitcnt vmcnt(4)" ::: "memory");
        __builtin_amdgcn_sched_barrier(0);

        f32x4 acc[2][3];
#pragma unroll
        for (int ta = 0; ta < 2; ++ta)
#pragma unroll
            for (int tm = 0; tm < 3; ++tm) acc[ta][tm] = {0.f, 0.f, 0.f, 0.f};

#pragma unroll
        for (int u = 0; u < 16; ++u) {
            short8 ahi = __builtin_bit_cast(short8, hb[u]);
            short8 alo = __builtin_bit_cast(short8, lbv[u]);
            const int ks = ks0 + u;
#pragma unroll
            for (int ta = 0; ta < 2; ++ta) {
                short8 bhi = *(const short8*)(&WBl[ta * 32768 + (ks * 2 + 0) * 512 + (lane << 3)]);
                short8 blo = *(const short8*)(&WBl[ta * 32768 + (ks * 2 + 1) * 512 + (lane << 3)]);
                acc[ta][0] = __builtin_amdgcn_mfma_f32_16x16x32_bf16(ahi, bhi, acc[ta][0], 0, 0, 0);
                acc[ta][1] = __builtin_amdgcn_mfma_f32_16x16x32_bf16(ahi, blo, acc[ta][1], 0, 0, 0);
                acc[ta][2] = __builtin_amdgcn_mfma_f32_16x16x32_bf16(alo, bhi, acc[ta][2], 0, 0, 0);
            }
        }

        // C tile -> LDS partials: lane (q,c), reg r = C[m=mt*16+q*4+r][tile c]
#pragma unroll
        for (int ta = 0; ta < 2; ++ta)
#pragma unroll
            for (int r = 0; r < 4; ++r)
                gates[kh][mt * 16 + q * 4 + r][ta * 16 + c] =
                    acc[ta][0][r] + acc[ta][1][r] + acc[ta][2][r];
        __syncthreads();   // S1 (also drains the xproj loads)

        asm volatile("s_waitcnt vmcnt(0)" ::: "memory");  // xq ready (usually free)
        __builtin_amdgcn_sched_barrier(0);

        // pointwise: thread (jj, b=lane); gate g at block-col g*8+jj
        //   -> tile (jj>>2), tile-col g*4+(jj&3); gate order i,j,f,o
        {
            const int b  = lane;
            const int tb = (jj >> 2) * 16 + (jj & 3);
            const float gi = gates[0][b][tb +  0] + gates[1][b][tb +  0] + xq0;
            const float gj = gates[0][b][tb +  4] + gates[1][b][tb +  4] + xq1;
            const float gf = gates[0][b][tb +  8] + gates[1][b][tb +  8] + xq2;
            const float go = gates[0][b][tb + 12] + gates[1][b][tb + 12] + xq3;

            const float c_old = cTl[jj * 64 + b];
            const float fgate = 1.f / (1.f + expf(-(gf + 1.0f)));  // forget bias
            const float igate = 1.f / (1.f + expf(-gi));
            const float ogate = 1.f / (1.f + expf(-go));
            const float cnew  = c_old * fgate + igate * tanhf(gj);
            const float hnew  = tanhf(cnew) * ogate;
            cTl[jj * 64 + b] = cnew;

            const unsigned short hi = f2bf(hnew);
            hEx[0][jj * 64 + b] = hi;
            hEx[1][jj * 64 + b] = f2bf(hnew - bf2f(hi));
            if (t == myseq - 1) fhT[(bk * 8 + jj) * 64 + b] = hnew;
        }
        __syncthreads();   // S2

        // ---- packed 16B h store (write-through to LLC) ----
        if (tid < 128) {
            unsigned a0 = hEx[sel][0 * 64 + bb], a1 = hEx[sel][1 * 64 + bb];
            unsigned a2 = hEx[sel][2 * 64 + bb], a3 = hEx[sel][3 * 64 + bb];
            unsigned a4 = hEx[sel][4 * 64 + bb], a5 = hEx[sel][5 * 64 + bb];
            unsigned a6 = hEx[sel][6 * 64 + bb], a7 = hEx[sel][7 * 64 + bb];
            u32x4 v;
            v.x = a0 | (a1 << 16);
            v.y = a2 | (a3 << 16);
            v.z = a4 | (a5 << 16);
            v.w = a6 | (a7 << 16);
            unsigned int* dstw = (unsigned int*)(sel ? nxtLo : nxtHi) + widx;
            asm volatile("global_store_dwordx4 %0, %1, off sc0 sc1"
                         :: "v"(dstw), "v"(v) : "memory");
        }

        // ---- release: drain h (+ rare fhT) stores, then arrive ----
        asm volatile("s_waitcnt vmcnt(0)" ::: "memory");
        __syncthreads();   // S3: all of this block's stores acked at the LLC
        const unsigned tgt = (unsigned)(t + 1);
        if (tid == 0) {
            unsigned old = __hip_atomic_fetch_add(&done[0], 1u,
                             __ATOMIC_RELAXED, __HIP_MEMORY_SCOPE_AGENT);
            if (old == tgt * (unsigned)NB - 1u) {
#pragma unroll
                for (int wg = 0; wg < 8; ++wg)
                    __hip_atomic_store(&done[32 + wg * 32], tgt,
                                       __ATOMIC_RELAXED, __HIP_MEMORY_SCOPE_AGENT);
            }
        }
        // ---- per-wave go poll (1 coalesced request per iteration) ----
        {
            const unsigned int* goP = &done[32 + wv * 32];
            while (__hip_atomic_load(goP, __ATOMIC_RELAXED,
                                     __HIP_MEMORY_SCOPE_AGENT) < tgt) {
                __builtin_amdgcn_s_sleep(4);
            }
        }
        __builtin_amdgcn_sched_barrier(0);   // no hoisting of next-step loads

        unsigned short* s;
        s = curHi; curHi = nxtHi; nxtHi = s;
        s = curLo; curLo = nxtLo; nxtLo = s;
    }
}

// ---------------------------------------------------------------------------
// Kernel C1: denseT[d][b] = relu(fh[b] . dense_w[:,d] + db[d])
__global__ __launch_bounds__(256) void dense_kernel(
    const float* __restrict__ fhT, const float* __restrict__ Wdf,
    const float* __restrict__ dbf, float* __restrict__ denseT)
{
    const int tid  = threadIdx.x;
    const int lane = tid & 63;
    const int wv   = __builtin_amdgcn_readfirstlane(tid >> 6);
    const int d0   = blockIdx.x * 16 + wv * 4;

    float acc[4] = {0.f, 0.f, 0.f, 0.f};
#pragma unroll 4
    for (int k = 0; k < H_; ++k) {
        float v = fhT[k * 64 + lane];
        const float* wr = Wdf + (long)k * D_ + d0;
        acc[0] += wr[0] * v;
        acc[1] += wr[1] * v;
        acc[2] += wr[2] * v;
        acc[3] += wr[3] * v;
    }
#pragma unroll
    for (int c = 0; c < 4; ++c) {
        float z = acc[c] + dbf[d0 + c];
        z = z > 0.f ? z : 0.f;
        denseT[(d0 + c) * 64 + lane] = z;
    }
}

// Kernel C2: logits; output dtype follows detected input dtype.
__global__ void logits_kernel(const float* __restrict__ denseT,
                              const float* __restrict__ Wpf,
                              const float* __restrict__ pbf,
                              const int* __restrict__ flag,
                              void* __restrict__ out)
{
    const int tid  = threadIdx.x;      // 128 threads: 2 waves
    const int lane = tid & 63;
    const int c    = __builtin_amdgcn_readfirstlane(tid >> 6);
    float acc = 0.f;
#pragma unroll 4
    for (int k = 0; k < D_; ++k)
        acc += denseT[k * 64 + lane] * Wpf[k * C_ + c];
    const float r = acc + pbf[c];
    if (*flag != 0) ((float*)out)[lane * C_ + c] = r;
    else            ((unsigned short*)out)[lane * C_ + c] = f2bf(r);
}

// ---------------------------------------------------------------------------
extern "C" void kernel_launch(void* const* d_in, const int* in_sizes, int n_in,
                              void* d_out, int out_size, void* d_ws, size_t ws_size,
                              hipStream_t stream)
{
    // Map inputs by unique flat element counts; fall back to positional.
    const int want[9] = {16384, 64, 25600000, 6291456, 4096, 524288, 512, 1024, 2};
    const void* p[9];
    for (int i = 0; i < 9; ++i) p[i] = d_in[i];
    if (n_in == 9) {
        bool ok = true;
        const void* q[9];
        for (int i = 0; i < 9; ++i) {
            int found = -1;
            for (int j = 0; j < 9; ++j) if (in_sizes[j] == want[i]) { found = j; break; }
            if (found < 0) { ok = false; break; }
            q[i] = d_in[found];
        }
        if (ok) for (int i = 0; i < 9; ++i) p[i] = q[i];
    }
    const int*  X      = (const int*)p[0];
    const int*  seqlen = (const int*)p[1];
    const void* emb    = p[2];
    const void* lk     = p[3];
    const void* lb     = p[4];
    const void* dw     = p[5];
    const void* dbm    = p[6];
    const void* pw     = p[7];
    const void* pbm    = p[8];

    float* w = (float*)d_ws;
    unsigned int* done = (unsigned int*)(w + OFF_BAR);
    int*          flag = (int*)done + 400;   // outside zeroed [0,384) range

    detect_kernel<<<1, 256, 0, stream>>>((const unsigned short*)emb, flag);

    prep_kernel<<<(PREP_TOTAL + 255) / 256, 256, 0, stream>>>(
        lk, lb, dw, dbm, pw, pbm, flag, w);

    xproj_kernel<<<dim3(64, 256), 256, 0, stream>>>(X, emb, flag,
                                                    w + OFF_WFX, w + OFF_BIAS,
                                                    w + OFF_XPROJ);

    lstm_persistent<<<NB, 512, 0, stream>>>((unsigned short*)(w + OFF_HH),
                                            w + OFF_FH,
                                            (const unsigned short*)(w + OFF_WB),
                                            w + OFF_XPROJ,
                                            seqlen, done);

    dense_kernel<<<32, 256, 0, stream>>>(w + OFF_FH, w + OFF_WD,
                                         w + OFF_DB, w + OFF_DEN);
    logits_kernel<<<1, 128, 0, stream>>>(w + OFF_DEN, w + OFF_WP,
                                         w + OFF_PB, flag, d_out);
}

// Round 7
// 3074.902 us; speedup vs baseline: 1.1172x; 1.1172x over previous
//
#include <hip/hip_runtime.h>
#include <hip/hip_bf16.h>

// Problem dims
#define B_   64
#define S_   256
#define E_   512
#define H_   1024
#define D_   512
#define C_   2
#define G4   4096   // 4*H
#define NB   128    // blocks in persistent recurrence

typedef __attribute__((ext_vector_type(8))) short short8;   // 8 bf16 (4 VGPRs)
typedef __attribute__((ext_vector_type(4))) float f32x4;
typedef __attribute__((ext_vector_type(4))) unsigned int u32x4;  // asm-safe 16B

__device__ __forceinline__ float bf2f(unsigned short u) {
    unsigned int x = ((unsigned int)u) << 16;
    return __uint_as_float(x);
}
__device__ __forceinline__ unsigned short f2bf(float f) {
    unsigned int x = __float_as_uint(f);
    unsigned int r = (x + 0x7fffu + ((x >> 16) & 1u)) >> 16;
    return (unsigned short)r;
}

// ---------------------------------------------------------------------------
// Kernel D: detect fp32 (flag=1) vs bf16 (flag=0) float inputs (probe emb).
__global__ void detect_kernel(const unsigned short* __restrict__ emb_u,
                              int* __restrict__ flag)
{
    __shared__ int cnt;
    if (threadIdx.x == 0) cnt = 0;
    __syncthreads();
    int bad = 0;
#pragma unroll
    for (int i = 0; i < 8; ++i) {
        unsigned short u = emb_u[threadIdx.x * 8 + i];
        float a = fabsf(bf2f(u));
        if (!(a < 4.0f)) bad = 1;
        else if (a != 0.0f && a < 1e-20f) bad = 1;
    }
    if (bad) atomicAdd(&cnt, 1);
    __syncthreads();
    if (threadIdx.x == 0) *flag = (cnt > 16) ? 1 : 0;
}

// ---------------------------------------------------------------------------
// Workspace float offsets
#define OFF_WFX   0L          // 2097152  (Wx rows 0..511, fp32 [k][n])
#define OFF_WB    2097152L    // 4194304 floats = 8.4M ushort: MFMA B-frags
#define OFF_BIAS  6291456L    // 4096
#define OFF_WD    6295552L    // 524288
#define OFF_DB    6819840L    // 512
#define OFF_WP    6820352L    // 1024
#define OFF_PB    6821376L    // 16 (2 used)
#define OFF_FH    6821392L    // 65536
#define OFF_DEN   6886928L    // 32768
#define OFF_HH    6919696L    // h state: 2 ushort bufs of 65536 (hiA, hiB);
                              //   h is SINGLE bf16 (lo residual dropped, r7)
#define OFF_BAR   7050768L    // 512 uints: ctr@0, go@32+w*32 (w=0..7), flag@400
#define OFF_XPROJ 7051280L    // 67108864

// Kernel P: convert/relayout weights (bf16 hi/lo MFMA B-frag order),
// zero fhT, t=0 h buffers, ctr/go flags (bar uints [0,384)).
#define PREP_TOTAL 6952834
__global__ void prep_kernel(const void* __restrict__ lk,
                            const void* __restrict__ lb,
                            const void* __restrict__ dw,
                            const void* __restrict__ dbm,
                            const void* __restrict__ pw,
                            const void* __restrict__ pbm,
                            const int* __restrict__ flag,
                            float* __restrict__ w)
{
    const bool f32 = (*flag != 0);
    long i = (long)blockIdx.x * 256 + threadIdx.x;
    if (i >= PREP_TOTAL) return;
#define CV(p, j) (f32 ? ((const float*)(p))[j] : bf2f(((const unsigned short*)(p))[j]))
    if (i < 2097152) { w[OFF_WFX + i] = CV(lk, i); return; }  i -= 2097152;
    if (i < 4194304) {
        // B-frag relayout (per 4-j group bk4): cols c=g*4+jj (n = g*1024 + bk4*4+jj).
        // lane l holds B[k = ks*32 + (l>>4)*8 + j][c = l&15], j=0..7.
        int j  = (int)(i & 7);
        int l  = (int)((i >> 3) & 63);
        int ks = (int)((i >> 9) & 31);
        int bk = (int)(i >> 14);
        int c  = l & 15, q = l >> 4;
        int k  = ks * 32 + q * 8 + j;
        int g  = c >> 2, jj = c & 3;
        long src = (long)(512 + k) * G4 + g * H_ + bk * 4 + jj;
        float v = CV(lk, src);
        unsigned short hi = f2bf(v);
        unsigned short lo = f2bf(v - bf2f(hi));
        unsigned short* WBu = (unsigned short*)(w + OFF_WB);
        long base = ((long)(bk * 32 + ks) * 2) * 512 + l * 8 + j;
        WBu[base]       = hi;   // term 0
        WBu[base + 512] = lo;   // term 1
        return;
    }  i -= 4194304;
    if (i < 4096)    { w[OFF_BIAS + i] = CV(lb, i);  return; }  i -= 4096;
    if (i < 524288)  { w[OFF_WD + i]   = CV(dw, i);  return; }  i -= 524288;
    if (i < 512)     { w[OFF_DB + i]   = CV(dbm, i); return; }  i -= 512;
    if (i < 1024)    { w[OFF_WP + i]   = CV(pw, i);  return; }  i -= 1024;
    if (i < 2)       { w[OFF_PB + i]   = CV(pbm, i); return; }  i -= 2;
    if (i < 65536)   { w[OFF_FH + i] = 0.f; return; }  i -= 65536;
    if (i < 65536)   { ((unsigned int*)(w + OFF_HH))[i] = 0u; return; }  i -= 65536;
    if (i < 384)     { ((unsigned int*)(w + OFF_BAR))[i] = 0u; return; }
#undef CV
}

// ---------------------------------------------------------------------------
// Kernel A: xprojT[t][n][b] = sum_e emb[X[b,t]][e] * Wfx[e][n] + bias[n]
__global__ __launch_bounds__(256) void xproj_kernel(
    const int* __restrict__ X,
    const void* __restrict__ emb,
    const int* __restrict__ flag,
    const float* __restrict__ Wfx,
    const float* __restrict__ biasf,
    float* __restrict__ xprojT)
{
    const int t    = blockIdx.y;
    const int cb   = blockIdx.x;
    const int tid  = threadIdx.x;
    const int lane = tid & 63;
    const int wv   = __builtin_amdgcn_readfirstlane(tid >> 6);
    const bool f32 = (*flag != 0);

    __shared__ float embT[128 * 64];
    __shared__ int   rowid[64];

    if (tid < 64) rowid[tid] = X[tid * S_ + t];
    __syncthreads();

    const int n0 = cb * 64 + wv * 16;
    float acc[16];
#pragma unroll
    for (int c = 0; c < 16; ++c) acc[c] = biasf[n0 + c];

    const long myrow = (long)rowid[lane] * E_;

    for (int kc = 0; kc < 4; ++kc) {
        const int k0 = kc * 128;
        if (f32) {
            const float4* src = (const float4*)((const float*)emb + myrow + k0 + wv * 32);
#pragma unroll
            for (int u = 0; u < 8; ++u) {
                float4 v = src[u];
                int kl = wv * 32 + u * 4;
                embT[(kl + 0) * 64 + lane] = v.x;
                embT[(kl + 1) * 64 + lane] = v.y;
                embT[(kl + 2) * 64 + lane] = v.z;
                embT[(kl + 3) * 64 + lane] = v.w;
            }
        } else {
            const uint4* src = (const uint4*)((const unsigned short*)emb + myrow + k0 + wv * 32);
#pragma unroll
            for (int u = 0; u < 4; ++u) {
                uint4 v = src[u];
                int kl = wv * 32 + u * 8;
                embT[(kl + 0) * 64 + lane] = bf2f((unsigned short)(v.x & 0xffff));
                embT[(kl + 1) * 64 + lane] = bf2f((unsigned short)(v.x >> 16));
                embT[(kl + 2) * 64 + lane] = bf2f((unsigned short)(v.y & 0xffff));
                embT[(kl + 3) * 64 + lane] = bf2f((unsigned short)(v.y >> 16));
                embT[(kl + 4) * 64 + lane] = bf2f((unsigned short)(v.z & 0xffff));
                embT[(kl + 5) * 64 + lane] = bf2f((unsigned short)(v.z >> 16));
                embT[(kl + 6) * 64 + lane] = bf2f((unsigned short)(v.w & 0xffff));
                embT[(kl + 7) * 64 + lane] = bf2f((unsigned short)(v.w >> 16));
            }
        }
        __syncthreads();

        const float* wbase = Wfx + (long)k0 * G4 + n0;
#pragma unroll 2
        for (int k = 0; k < 128; ++k) {
            float hv = embT[k * 64 + lane];
            const float* wr = wbase + (long)k * G4;
#pragma unroll
            for (int c = 0; c < 16; ++c) acc[c] += wr[c] * hv;
        }
        __syncthreads();
    }

    float* dst = xprojT + ((long)t * G4 + n0) * 64 + lane;
#pragma unroll
    for (int c = 0; c < 16; ++c) dst[c * 64] = acc[c];
}

// ---------------------------------------------------------------------------
// Persistent MFMA LSTM recurrence. 128 blocks x 512 thr (8 waves).
// Block bk owns h-dims j = bk*8..bk*8+7 -> 32 gate cols (two 16-col tiles).
// Waves = 4 m-tiles x 2 k-halves. Weights LDS-resident (128 KB).
//
// FENCELESS LLC protocol (rounds 2-6, verified): h moves via L1/L2-bypassing
// (sc0 sc1) accesses through the coherent LLC; release = per-wave vmcnt(0)
// drain of h stores before __syncthreads; acquire = bypassing loads. No
// cache-maintenance walks. Double-buffered h bounds skew to <=1 step.
// Barrier: atomicAdd-last-arriver + per-wave replicated go lines (round 6).
//
// NEW this round (traffic halving — the data phase is the wall):
//  * h carried as a SINGLE bf16 (lo residual dropped). Weights stay hi/lo
//    bf16 (2 MFMA terms: h*Whi + h*Wlo), so weight precision is unchanged;
//    only h is quantized to bf16 (rel err 2^-9). Final h for the dense head
//    is stored as exact fp32 (fhT), so only the recurrent path sees it.
//  * Broadcast traffic halves: 16 loads/wave (16 MB/step chip-wide), h
//    stores halve (64 x 16B per block), MFMA count 96 -> 64 per wave.
__global__ __launch_bounds__(512, 2) void lstm_persistent(
    unsigned short* __restrict__ hU,     // hiA | hiB (65536 ushorts each)
    float* __restrict__ fhT,
    const unsigned short* __restrict__ WBg,
    const float* __restrict__ xprojT,
    const int* __restrict__ seqlen, unsigned int* __restrict__ done)
{
    const int tid  = threadIdx.x;
    const int lane = tid & 63;
    const int wv   = __builtin_amdgcn_readfirstlane(tid >> 6);  // 0..7
    const int bk   = blockIdx.x;        // 0..127
    const int mt   = wv & 3;            // m-tile (batch rows mt*16..+15)
    const int kh   = wv >> 2;           // k-half (ks in [kh*16, kh*16+16))

    __shared__ unsigned short WBl[65536];   // 128 KB B-frags (2 tiles)
    __shared__ float gates[2][64][33];      // [kh][m][tile*16+c] partials
    __shared__ float cTl[512];              // [jj][b] cell state
    __shared__ unsigned short hEx[512];     // [jj*64+b] h exchange (bf16)

    // stage weight frags (once) + init c
    {
        const uint4* src = (const uint4*)(WBg + (long)bk * 65536);
        uint4* dst = (uint4*)WBl;
#pragma unroll
        for (int u = 0; u < 16; ++u) dst[tid + u * 512] = src[tid + u * 512];
        cTl[tid] = 0.f;
    }
    __syncthreads();

    const int myseq = seqlen[lane];
    const int q = lane >> 4, c = lane & 15;
    const int jj = wv;                  // pointwise j owner: j = bk*8 + jj

    unsigned short* hiA = hU;
    unsigned short* hiB = hU + 65536;
    unsigned short *curHi = hiA, *nxtHi = hiB;

    // Packed 16B h-store role: 64 threads (wave 0; bb = batch) each store
    // one 16B vec = j-pairs 0..3 for batch bb.  Dword index:
    //   (bk>>2)*1024 + (bb>>4)*256 + (bk&3)*64 + (bb&15)*4   (16B aligned)
    const int bb  = tid & 63;
    const long widx = (long)(bk >> 2) * 1024 + (bb >> 4) * 256
                    + (bk & 3) * 64 + (bb & 15) * 4;

    const long xoff = (long)(bk * 8 + jj);

    for (int t = 0; t < S_; ++t) {
        // ---- A-frag loads: m-tile mt, k-half kh; 16 x 16B, LLC-coherent ----
        const unsigned short* hiP = curHi + ((long)mt * 64 + lane) * 8;
        const int ks0 = kh * 16;

        u32x4 hb[16];
#pragma unroll
        for (int u = 0; u < 16; ++u) {
            asm volatile("global_load_dwordx4 %0, %1, off sc0 sc1"
                         : "=v"(hb[u])
                         : "v"(hiP + (long)(ks0 + u) * 2048) : "memory");
        }
        // xproj loads issued AFTER the h loads (drained by S1 under MFMA)
        float xq0, xq1, xq2, xq3;
        {
            const long xb = (long)t * G4 + xoff;
            const float* x0 = xprojT + (xb + 0 * H_) * 64 + lane;
            const float* x1 = xprojT + (xb + 1 * H_) * 64 + lane;
            const float* x2 = xprojT + (xb + 2 * H_) * 64 + lane;
            const float* x3 = xprojT + (xb + 3 * H_) * 64 + lane;
            asm volatile("global_load_dword %0, %1, off" : "=v"(xq0) : "v"(x0) : "memory");
            asm volatile("global_load_dword %0, %1, off" : "=v"(xq1) : "v"(x1) : "memory");
            asm volatile("global_load_dword %0, %1, off" : "=v"(xq2) : "v"(x2) : "memory");
            asm volatile("global_load_dword %0, %1, off" : "=v"(xq3) : "v"(x3) : "memory");
        }
        // wait for the 16 h loads only (4 xproj still outstanding)
        asm volatile("s_waitcnt vmcnt(4)" ::: "memory");
        __builtin_amdgcn_sched_barrier(0);

        f32x4 acc[2][2];
#pragma unroll
        for (int ta = 0; ta < 2; ++ta)
#pragma unroll
            for (int tm = 0; tm < 2; ++tm) acc[ta][tm] = {0.f, 0.f, 0.f, 0.f};

#pragma unroll
        for (int u = 0; u < 16; ++u) {
            short8 ahi = __builtin_bit_cast(short8, hb[u]);
            const int ks = ks0 + u;
#pragma unroll
            for (int ta = 0; ta < 2; ++ta) {
                short8 bhi = *(const short8*)(&WBl[ta * 32768 + (ks * 2 + 0) * 512 + (lane << 3)]);
                short8 blo = *(const short8*)(&WBl[ta * 32768 + (ks * 2 + 1) * 512 + (lane << 3)]);
                acc[ta][0] = __builtin_amdgcn_mfma_f32_16x16x32_bf16(ahi, bhi, acc[ta][0], 0, 0, 0);
                acc[ta][1] = __builtin_amdgcn_mfma_f32_16x16x32_bf16(ahi, blo, acc[ta][1], 0, 0, 0);
            }
        }

        // C tile -> LDS partials: lane (q,c), reg r = C[m=mt*16+q*4+r][tile c]
#pragma unroll
        for (int ta = 0; ta < 2; ++ta)
#pragma unroll
            for (int r = 0; r < 4; ++r)
                gates[kh][mt * 16 + q * 4 + r][ta * 16 + c] =
                    acc[ta][0][r] + acc[ta][1][r];
        __syncthreads();   // S1 (also drains the xproj loads)

        asm volatile("s_waitcnt vmcnt(0)" ::: "memory");  // xq ready (usually free)
        __builtin_amdgcn_sched_barrier(0);

        // pointwise: thread (jj, b=lane); gate g at block-col g*8+jj
        //   -> tile (jj>>2), tile-col g*4+(jj&3); gate order i,j,f,o
        {
            const int b  = lane;
            const int tb = (jj >> 2) * 16 + (jj & 3);
            const float gi = gates[0][b][tb +  0] + gates[1][b][tb +  0] + xq0;
            const float gj = gates[0][b][tb +  4] + gates[1][b][tb +  4] + xq1;
            const float gf = gates[0][b][tb +  8] + gates[1][b][tb +  8] + xq2;
            const float go = gates[0][b][tb + 12] + gates[1][b][tb + 12] + xq3;

            const float c_old = cTl[jj * 64 + b];
            const float fgate = 1.f / (1.f + expf(-(gf + 1.0f)));  // forget bias
            const float igate = 1.f / (1.f + expf(-gi));
            const float ogate = 1.f / (1.f + expf(-go));
            const float cnew  = c_old * fgate + igate * tanhf(gj);
            const float hnew  = tanhf(cnew) * ogate;
            cTl[jj * 64 + b] = cnew;

            hEx[jj * 64 + b] = f2bf(hnew);
            if (t == myseq - 1) fhT[(bk * 8 + jj) * 64 + b] = hnew;
        }
        __syncthreads();   // S2

        // ---- packed 16B h store (write-through to LLC), wave 0 only ----
        if (tid < 64) {
            unsigned a0 = hEx[0 * 64 + bb], a1 = hEx[1 * 64 + bb];
            unsigned a2 = hEx[2 * 64 + bb], a3 = hEx[3 * 64 + bb];
            unsigned a4 = hEx[4 * 64 + bb], a5 = hEx[5 * 64 + bb];
            unsigned a6 = hEx[6 * 64 + bb], a7 = hEx[7 * 64 + bb];
            u32x4 v;
            v.x = a0 | (a1 << 16);
            v.y = a2 | (a3 << 16);
            v.z = a4 | (a5 << 16);
            v.w = a6 | (a7 << 16);
            unsigned int* dstw = (unsigned int*)nxtHi + widx;
            asm volatile("global_store_dwordx4 %0, %1, off sc0 sc1"
                         :: "v"(dstw), "v"(v) : "memory");
        }

        // ---- release: drain h (+ rare fhT) stores, then arrive ----
        asm volatile("s_waitcnt vmcnt(0)" ::: "memory");
        __syncthreads();   // S3: all of this block's stores acked at the LLC
        const unsigned tgt = (unsigned)(t + 1);
        if (tid == 0) {
            unsigned old = __hip_atomic_fetch_add(&done[0], 1u,
                             __ATOMIC_RELAXED, __HIP_MEMORY_SCOPE_AGENT);
            if (old == tgt * (unsigned)NB - 1u) {
#pragma unroll
                for (int wg = 0; wg < 8; ++wg)
                    __hip_atomic_store(&done[32 + wg * 32], tgt,
                                       __ATOMIC_RELAXED, __HIP_MEMORY_SCOPE_AGENT);
            }
        }
        // ---- per-wave go poll (1 coalesced request per iteration) ----
        {
            const unsigned int* goP = &done[32 + wv * 32];
            while (__hip_atomic_load(goP, __ATOMIC_RELAXED,
                                     __HIP_MEMORY_SCOPE_AGENT) < tgt) {
                __builtin_amdgcn_s_sleep(4);
            }
        }
        __builtin_amdgcn_sched_barrier(0);   // no hoisting of next-step loads

        unsigned short* s;
        s = curHi; curHi = nxtHi; nxtHi = s;
    }
}

// ---------------------------------------------------------------------------
// Kernel C1: denseT[d][b] = relu(fh[b] . dense_w[:,d] + db[d])
__global__ __launch_bounds__(256) void dense_kernel(
    const float* __restrict__ fhT, const float* __restrict__ Wdf,
    const float* __restrict__ dbf, float* __restrict__ denseT)
{
    const int tid  = threadIdx.x;
    const int lane = tid & 63;
    const int wv   = __builtin_amdgcn_readfirstlane(tid >> 6);
    const int d0   = blockIdx.x * 16 + wv * 4;

    float acc[4] = {0.f, 0.f, 0.f, 0.f};
#pragma unroll 4
    for (int k = 0; k < H_; ++k) {
        float v = fhT[k * 64 + lane];
        const float* wr = Wdf + (long)k * D_ + d0;
        acc[0] += wr[0] * v;
        acc[1] += wr[1] * v;
        acc[2] += wr[2] * v;
        acc[3] += wr[3] * v;
    }
#pragma unroll
    for (int c = 0; c < 4; ++c) {
        float z = acc[c] + dbf[d0 + c];
        z = z > 0.f ? z : 0.f;
        denseT[(d0 + c) * 64 + lane] = z;
    }
}

// Kernel C2: logits; output dtype follows detected input dtype.
__global__ void logits_kernel(const float* __restrict__ denseT,
                              const float* __restrict__ Wpf,
                              const float* __restrict__ pbf,
                              const int* __restrict__ flag,
                              void* __restrict__ out)
{
    const int tid  = threadIdx.x;      // 128 threads: 2 waves
    const int lane = tid & 63;
    const int c    = __builtin_amdgcn_readfirstlane(tid >> 6);
    float acc = 0.f;
#pragma unroll 4
    for (int k = 0; k < D_; ++k)
        acc += denseT[k * 64 + lane] * Wpf[k * C_ + c];
    const float r = acc + pbf[c];
    if (*flag != 0) ((float*)out)[lane * C_ + c] = r;
    else            ((unsigned short*)out)[lane * C_ + c] = f2bf(r);
}

// ---------------------------------------------------------------------------
extern "C" void kernel_launch(void* const* d_in, const int* in_sizes, int n_in,
                              void* d_out, int out_size, void* d_ws, size_t ws_size,
                              hipStream_t stream)
{
    // Map inputs by unique flat element counts; fall back to positional.
    const int want[9] = {16384, 64, 25600000, 6291456, 4096, 524288, 512, 1024, 2};
    const void* p[9];
    for (int i = 0; i < 9; ++i) p[i] = d_in[i];
    if (n_in == 9) {
        bool ok = true;
        const void* q[9];
        for (int i = 0; i < 9; ++i) {
            int found = -1;
            for (int j = 0; j < 9; ++j) if (in_sizes[j] == want[i]) { found = j; break; }
            if (found < 0) { ok = false; break; }
            q[i] = d_in[found];
        }
        if (ok) for (int i = 0; i < 9; ++i) p[i] = q[i];
    }
    const int*  X      = (const int*)p[0];
    const int*  seqlen = (const int*)p[1];
    const void* emb    = p[2];
    const void* lk     = p[3];
    const void* lb     = p[4];
    const void* dw     = p[5];
    const void* dbm    = p[6];
    const void* pw     = p[7];
    const void* pbm    = p[8];

    float* w = (float*)d_ws;
    unsigned int* done = (unsigned int*)(w + OFF_BAR);
    int*          flag = (int*)done + 400;   // outside zeroed [0,384) range

    detect_kernel<<<1, 256, 0, stream>>>((const unsigned short*)emb, flag);

    prep_kernel<<<(PREP_TOTAL + 255) / 256, 256, 0, stream>>>(
        lk, lb, dw, dbm, pw, pbm, flag, w);

    xproj_kernel<<<dim3(64, 256), 256, 0, stream>>>(X, emb, flag,
                                                    w + OFF_WFX, w + OFF_BIAS,
                                                    w + OFF_XPROJ);

    lstm_persistent<<<NB, 512, 0, stream>>>((unsigned short*)(w + OFF_HH),
                                            w + OFF_FH,
                                            (const unsigned short*)(w + OFF_WB),
                                            w + OFF_XPROJ,
                                            seqlen, done);

    dense_kernel<<<32, 256, 0, stream>>>(w + OFF_FH, w + OFF_WD,
                                         w + OFF_DB, w + OFF_DEN);
    logits_kernel<<<1, 128, 0, stream>>>(w + OFF_DEN, w + OFF_WP,
                                         w + OFF_PB, flag, d_out);
}

// Round 8
// 2677.163 us; speedup vs baseline: 1.2831x; 1.1486x over previous
//
#include <hip/hip_runtime.h>
#include <hip/hip_bf16.h>

// Problem dims
#define B_   64
#define S_   256
#define E_   512
#define H_   1024
#define D_   512
#define C_   2
#define G4   4096   // 4*H
#define NB   128    // blocks in persistent recurrence

typedef __attribute__((ext_vector_type(8))) short short8;   // 8 bf16 (4 VGPRs)
typedef __attribute__((ext_vector_type(4))) float f32x4;
typedef __attribute__((ext_vector_type(4))) unsigned int u32x4;  // asm-safe 16B

__device__ __forceinline__ float bf2f(unsigned short u) {
    unsigned int x = ((unsigned int)u) << 16;
    return __uint_as_float(x);
}
__device__ __forceinline__ unsigned short f2bf(float f) {
    unsigned int x = __float_as_uint(f);
    unsigned int r = (x + 0x7fffu + ((x >> 16) & 1u)) >> 16;
    return (unsigned short)r;
}

// ---------------------------------------------------------------------------
// Kernel D: detect fp32 (flag=1) vs bf16 (flag=0) float inputs (probe emb).
__global__ void detect_kernel(const unsigned short* __restrict__ emb_u,
                              int* __restrict__ flag)
{
    __shared__ int cnt;
    if (threadIdx.x == 0) cnt = 0;
    __syncthreads();
    int bad = 0;
#pragma unroll
    for (int i = 0; i < 8; ++i) {
        unsigned short u = emb_u[threadIdx.x * 8 + i];
        float a = fabsf(bf2f(u));
        if (!(a < 4.0f)) bad = 1;
        else if (a != 0.0f && a < 1e-20f) bad = 1;
    }
    if (bad) atomicAdd(&cnt, 1);
    __syncthreads();
    if (threadIdx.x == 0) *flag = (cnt > 16) ? 1 : 0;
}

// ---------------------------------------------------------------------------
// Workspace float offsets
#define OFF_WBX   0L          // 2097152 floats = 4M ushorts: x-weight B-frags
                              //   WBX[nt(256)][ks(16)][term][lane][8] (hi,lo)
#define OFF_WB    2097152L    // 4194304 floats = 8.4M ushort: recurrent B-frags
#define OFF_BIAS  6291456L    // 4096
#define OFF_WD    6295552L    // 524288
#define OFF_DB    6819840L    // 512
#define OFF_WP    6820352L    // 1024
#define OFF_PB    6821376L    // 16 (2 used)
#define OFF_FH    6821392L    // 65536
#define OFF_DEN   6886928L    // 32768
#define OFF_HH    6919696L    // h state: 2 ushort bufs of 65536 (hiA, hiB);
                              //   h is SINGLE bf16 (lo residual dropped, r7)
#define OFF_BAR   7050768L    // 512 uints: ctr@0, go@32+w*32 (w=0..7), flag@400
#define OFF_XPROJ 7051280L    // 67108864

// Kernel P: build WBX (x-weight frags) + WB (recurrent frags), copy bias/
// dense/pred params, zero fhT, t=0 h buffers, ctr/go flags.
#define PREP_TOTAL 6952834
__global__ void prep_kernel(const void* __restrict__ lk,
                            const void* __restrict__ lb,
                            const void* __restrict__ dw,
                            const void* __restrict__ dbm,
                            const void* __restrict__ pw,
                            const void* __restrict__ pbm,
                            const int* __restrict__ flag,
                            float* __restrict__ w)
{
    const bool f32 = (*flag != 0);
    long i = (long)blockIdx.x * 256 + threadIdx.x;
    if (i >= PREP_TOTAL) return;
#define CV(p, j) (f32 ? ((const float*)(p))[j] : bf2f(((const unsigned short*)(p))[j]))
    if (i < 2097152) {
        // WBX frag build: item = [nt(256)][ks(16)][lane(64)][j(8)],
        // writes hi (term0) and lo (term1). Source: lk rows 0..511 (x part),
        //   k = ks*32 + (l>>4)*8 + j, n = nt*16 + (l&15).
        int j  = (int)(i & 7);
        int l  = (int)((i >> 3) & 63);
        int ks = (int)((i >> 9) & 15);
        int nt = (int)(i >> 13);
        int k  = ks * 32 + (l >> 4) * 8 + j;
        int n  = nt * 16 + (l & 15);
        long src = (long)k * G4 + n;
        float v = CV(lk, src);
        unsigned short hi = f2bf(v);
        unsigned short lo = f2bf(v - bf2f(hi));
        unsigned short* WBXu = (unsigned short*)(w + OFF_WBX);
        long base = ((long)(nt * 16 + ks) * 2) * 512 + l * 8 + j;
        WBXu[base]       = hi;   // term 0
        WBXu[base + 512] = lo;   // term 1
        return;
    }  i -= 2097152;
    if (i < 4194304) {
        // Recurrent B-frag relayout (unchanged from prior rounds).
        int j  = (int)(i & 7);
        int l  = (int)((i >> 3) & 63);
        int ks = (int)((i >> 9) & 31);
        int bk = (int)(i >> 14);
        int c  = l & 15, q = l >> 4;
        int k  = ks * 32 + q * 8 + j;
        int g  = c >> 2, jj = c & 3;
        long src = (long)(512 + k) * G4 + g * H_ + bk * 4 + jj;
        float v = CV(lk, src);
        unsigned short hi = f2bf(v);
        unsigned short lo = f2bf(v - bf2f(hi));
        unsigned short* WBu = (unsigned short*)(w + OFF_WB);
        long base = ((long)(bk * 32 + ks) * 2) * 512 + l * 8 + j;
        WBu[base]       = hi;   // term 0
        WBu[base + 512] = lo;   // term 1
        return;
    }  i -= 4194304;
    if (i < 4096)    { w[OFF_BIAS + i] = CV(lb, i);  return; }  i -= 4096;
    if (i < 524288)  { w[OFF_WD + i]   = CV(dw, i);  return; }  i -= 524288;
    if (i < 512)     { w[OFF_DB + i]   = CV(dbm, i); return; }  i -= 512;
    if (i < 1024)    { w[OFF_WP + i]   = CV(pw, i);  return; }  i -= 1024;
    if (i < 2)       { w[OFF_PB + i]   = CV(pbm, i); return; }  i -= 2;
    if (i < 65536)   { w[OFF_FH + i] = 0.f; return; }  i -= 65536;
    if (i < 65536)   { ((unsigned int*)(w + OFF_HH))[i] = 0u; return; }  i -= 65536;
    if (i < 384)     { ((unsigned int*)(w + OFF_BAR))[i] = 0u; return; }
#undef CV
}

// ---------------------------------------------------------------------------
// Kernel A v2 (MFMA): xprojT[t][n][b] = sum_e emb[X[b,t]][e]*Wx[e][n] + bias[n]
// Grid (t=256, cb=64) x 512 thr (8 waves = 4 m-tiles x 2 tile-pairs).
// Stage 64 gathered emb rows as hi/lo bf16 A-frags in LDS (128 KB), then
// 16 ks x 2 tiles x 3 hi/lo terms of mfma_16x16x32_bf16 per wave.
// B-frags (WBX) stream from global; blockIdx.x = t so consecutive blocks
// reuse the same 128 KB WBX slice (L2-hot). Output layout unchanged.
__global__ __launch_bounds__(512) void xproj_kernel(
    const int* __restrict__ X,
    const void* __restrict__ emb,
    const int* __restrict__ flag,
    const unsigned short* __restrict__ WBXu,
    const float* __restrict__ biasf,
    float* __restrict__ xprojT)
{
    const int t    = blockIdx.x;
    const int cb   = blockIdx.y;
    const int tid  = threadIdx.x;
    const int lane = tid & 63;
    const int wv   = __builtin_amdgcn_readfirstlane(tid >> 6);  // 0..7
    const int mt   = wv & 3;            // m-tile (batch rows mt*16..+15)
    const int nh   = wv >> 2;           // tile-pair (tiles nh*2, nh*2+1)
    const bool f32 = (*flag != 0);

    __shared__ unsigned short Ahi[32768];   // [ks(16)][mt(4)][lane(64)][8]
    __shared__ unsigned short Alo[32768];
    __shared__ int rowid[64];

    if (tid < 64) rowid[tid] = X[tid * S_ + t];
    __syncthreads();

    // ---- stage emb rows -> A-frags (hi/lo bf16) ----
    {
        const int b   = tid >> 3;       // row 0..63
        const int e0  = (tid & 7) * 64; // 64 elems per thread
        const long rb = (long)rowid[b] * E_;
        const int mtb = b >> 4, b15 = b & 15;
        if (f32) {
            const float* src = (const float*)emb + rb + e0;
#pragma unroll
            for (int u = 0; u < 8; ++u) {
                const int e  = e0 + u * 8;
                const int ks = e >> 5;
                const int lf = ((e >> 3) & 3) * 16 + b15;
                const int base = ((ks * 4 + mtb) * 64 + lf) * 8;
                union { unsigned short s[8]; short8 v; } h, l;
#pragma unroll
                for (int k2 = 0; k2 < 8; ++k2) {
                    float v = src[u * 8 + k2];
                    unsigned short hb = f2bf(v);
                    h.s[k2] = hb;
                    l.s[k2] = f2bf(v - bf2f(hb));
                }
                *(short8*)(Ahi + base) = h.v;
                *(short8*)(Alo + base) = l.v;
            }
        } else {
            const unsigned short* src = (const unsigned short*)emb + rb + e0;
            const short8 z = {0, 0, 0, 0, 0, 0, 0, 0};
#pragma unroll
            for (int u = 0; u < 8; ++u) {
                const int e  = e0 + u * 8;
                const int ks = e >> 5;
                const int lf = ((e >> 3) & 3) * 16 + b15;
                const int base = ((ks * 4 + mtb) * 64 + lf) * 8;
                *(short8*)(Ahi + base) = *(const short8*)(src + u * 8);
                *(short8*)(Alo + base) = z;
            }
        }
    }
    __syncthreads();

    // ---- MFMA: 16 ks x 2 tiles x 3 terms per wave ----
    f32x4 acc[2][3];
#pragma unroll
    for (int ta = 0; ta < 2; ++ta)
#pragma unroll
        for (int tm = 0; tm < 3; ++tm) acc[ta][tm] = {0.f, 0.f, 0.f, 0.f};

    const int nt0 = cb * 4 + nh * 2;
#pragma unroll
    for (int ks = 0; ks < 16; ++ks) {
        short8 ahi = *(const short8*)(Ahi + ((ks * 4 + mt) * 64 + lane) * 8);
        short8 alo = *(const short8*)(Alo + ((ks * 4 + mt) * 64 + lane) * 8);
#pragma unroll
        for (int ta = 0; ta < 2; ++ta) {
            const long wb = ((long)((nt0 + ta) * 16 + ks) * 2) * 512 + lane * 8;
            short8 bhi = *(const short8*)(WBXu + wb);
            short8 blo = *(const short8*)(WBXu + wb + 512);
            acc[ta][0] = __builtin_amdgcn_mfma_f32_16x16x32_bf16(ahi, bhi, acc[ta][0], 0, 0, 0);
            acc[ta][1] = __builtin_amdgcn_mfma_f32_16x16x32_bf16(ahi, blo, acc[ta][1], 0, 0, 0);
            acc[ta][2] = __builtin_amdgcn_mfma_f32_16x16x32_bf16(alo, bhi, acc[ta][2], 0, 0, 0);
        }
    }

    // ---- epilogue: bias + store (C layout: col=lane&15, row=(lane>>4)*4+r) ----
    const int col = lane & 15, rg = lane >> 4;
#pragma unroll
    for (int ta = 0; ta < 2; ++ta) {
        const int n = (nt0 + ta) * 16 + col;
        const float bz = biasf[n];
        float4 o;
        o.x = acc[ta][0][0] + acc[ta][1][0] + acc[ta][2][0] + bz;
        o.y = acc[ta][0][1] + acc[ta][1][1] + acc[ta][2][1] + bz;
        o.z = acc[ta][0][2] + acc[ta][1][2] + acc[ta][2][2] + bz;
        o.w = acc[ta][0][3] + acc[ta][1][3] + acc[ta][2][3] + bz;
        *(float4*)(xprojT + ((long)t * G4 + n) * 64 + mt * 16 + rg * 4) = o;
    }
}

// ---------------------------------------------------------------------------
// Persistent MFMA LSTM recurrence (round 7, unchanged). 128 blocks x 512 thr.
// FENCELESS LLC protocol; h single bf16; atomicAdd-last-arriver barrier.
__global__ __launch_bounds__(512, 2) void lstm_persistent(
    unsigned short* __restrict__ hU,     // hiA | hiB (65536 ushorts each)
    float* __restrict__ fhT,
    const unsigned short* __restrict__ WBg,
    const float* __restrict__ xprojT,
    const int* __restrict__ seqlen, unsigned int* __restrict__ done)
{
    const int tid  = threadIdx.x;
    const int lane = tid & 63;
    const int wv   = __builtin_amdgcn_readfirstlane(tid >> 6);  // 0..7
    const int bk   = blockIdx.x;        // 0..127
    const int mt   = wv & 3;            // m-tile (batch rows mt*16..+15)
    const int kh   = wv >> 2;           // k-half (ks in [kh*16, kh*16+16))

    __shared__ unsigned short WBl[65536];   // 128 KB B-frags (2 tiles)
    __shared__ float gates[2][64][33];      // [kh][m][tile*16+c] partials
    __shared__ float cTl[512];              // [jj][b] cell state
    __shared__ unsigned short hEx[512];     // [jj*64+b] h exchange (bf16)

    // stage weight frags (once) + init c
    {
        const uint4* src = (const uint4*)(WBg + (long)bk * 65536);
        uint4* dst = (uint4*)WBl;
#pragma unroll
        for (int u = 0; u < 16; ++u) dst[tid + u * 512] = src[tid + u * 512];
        cTl[tid] = 0.f;
    }
    __syncthreads();

    const int myseq = seqlen[lane];
    const int q = lane >> 4, c = lane & 15;
    const int jj = wv;                  // pointwise j owner: j = bk*8 + jj

    unsigned short* hiA = hU;
    unsigned short* hiB = hU + 65536;
    unsigned short *curHi = hiA, *nxtHi = hiB;

    const int bb  = tid & 63;
    const long widx = (long)(bk >> 2) * 1024 + (bb >> 4) * 256
                    + (bk & 3) * 64 + (bb & 15) * 4;

    const long xoff = (long)(bk * 8 + jj);

    for (int t = 0; t < S_; ++t) {
        // ---- A-frag loads: m-tile mt, k-half kh; 16 x 16B, LLC-coherent ----
        const unsigned short* hiP = curHi + ((long)mt * 64 + lane) * 8;
        const int ks0 = kh * 16;

        u32x4 hb[16];
#pragma unroll
        for (int u = 0; u < 16; ++u) {
            asm volatile("global_load_dwordx4 %0, %1, off sc0 sc1"
                         : "=v"(hb[u])
                         : "v"(hiP + (long)(ks0 + u) * 2048) : "memory");
        }
        // xproj loads issued AFTER the h loads (drained by S1 under MFMA)
        float xq0, xq1, xq2, xq3;
        {
            const long xb = (long)t * G4 + xoff;
            const float* x0 = xprojT + (xb + 0 * H_) * 64 + lane;
            const float* x1 = xprojT + (xb + 1 * H_) * 64 + lane;
            const float* x2 = xprojT + (xb + 2 * H_) * 64 + lane;
            const float* x3 = xprojT + (xb + 3 * H_) * 64 + lane;
            asm volatile("global_load_dword %0, %1, off" : "=v"(xq0) : "v"(x0) : "memory");
            asm volatile("global_load_dword %0, %1, off" : "=v"(xq1) : "v"(x1) : "memory");
            asm volatile("global_load_dword %0, %1, off" : "=v"(xq2) : "v"(x2) : "memory");
            asm volatile("global_load_dword %0, %1, off" : "=v"(xq3) : "v"(x3) : "memory");
        }
        // wait for the 16 h loads only (4 xproj still outstanding)
        asm volatile("s_waitcnt vmcnt(4)" ::: "memory");
        __builtin_amdgcn_sched_barrier(0);

        f32x4 acc[2][2];
#pragma unroll
        for (int ta = 0; ta < 2; ++ta)
#pragma unroll
            for (int tm = 0; tm < 2; ++tm) acc[ta][tm] = {0.f, 0.f, 0.f, 0.f};

#pragma unroll
        for (int u = 0; u < 16; ++u) {
            short8 ahi = __builtin_bit_cast(short8, hb[u]);
            const int ks = ks0 + u;
#pragma unroll
            for (int ta = 0; ta < 2; ++ta) {
                short8 bhi = *(const short8*)(&WBl[ta * 32768 + (ks * 2 + 0) * 512 + (lane << 3)]);
                short8 blo = *(const short8*)(&WBl[ta * 32768 + (ks * 2 + 1) * 512 + (lane << 3)]);
                acc[ta][0] = __builtin_amdgcn_mfma_f32_16x16x32_bf16(ahi, bhi, acc[ta][0], 0, 0, 0);
                acc[ta][1] = __builtin_amdgcn_mfma_f32_16x16x32_bf16(ahi, blo, acc[ta][1], 0, 0, 0);
            }
        }

        // C tile -> LDS partials: lane (q,c), reg r = C[m=mt*16+q*4+r][tile c]
#pragma unroll
        for (int ta = 0; ta < 2; ++ta)
#pragma unroll
            for (int r = 0; r < 4; ++r)
                gates[kh][mt * 16 + q * 4 + r][ta * 16 + c] =
                    acc[ta][0][r] + acc[ta][1][r];
        __syncthreads();   // S1 (also drains the xproj loads)

        asm volatile("s_waitcnt vmcnt(0)" ::: "memory");  // xq ready (usually free)
        __builtin_amdgcn_sched_barrier(0);

        // pointwise: thread (jj, b=lane); gate g at block-col g*8+jj
        //   -> tile (jj>>2), tile-col g*4+(jj&3); gate order i,j,f,o
        {
            const int b  = lane;
            const int tb = (jj >> 2) * 16 + (jj & 3);
            const float gi = gates[0][b][tb +  0] + gates[1][b][tb +  0] + xq0;
            const float gj = gates[0][b][tb +  4] + gates[1][b][tb +  4] + xq1;
            const float gf = gates[0][b][tb +  8] + gates[1][b][tb +  8] + xq2;
            const float go = gates[0][b][tb + 12] + gates[1][b][tb + 12] + xq3;

            const float c_old = cTl[jj * 64 + b];
            const float fgate = 1.f / (1.f + expf(-(gf + 1.0f)));  // forget bias
            const float igate = 1.f / (1.f + expf(-gi));
            const float ogate = 1.f / (1.f + expf(-go));
            const float cnew  = c_old * fgate + igate * tanhf(gj);
            const float hnew  = tanhf(cnew) * ogate;
            cTl[jj * 64 + b] = cnew;

            hEx[jj * 64 + b] = f2bf(hnew);
            if (t == myseq - 1) fhT[(bk * 8 + jj) * 64 + b] = hnew;
        }
        __syncthreads();   // S2

        // ---- packed 16B h store (write-through to LLC), wave 0 only ----
        if (tid < 64) {
            unsigned a0 = hEx[0 * 64 + bb], a1 = hEx[1 * 64 + bb];
            unsigned a2 = hEx[2 * 64 + bb], a3 = hEx[3 * 64 + bb];
            unsigned a4 = hEx[4 * 64 + bb], a5 = hEx[5 * 64 + bb];
            unsigned a6 = hEx[6 * 64 + bb], a7 = hEx[7 * 64 + bb];
            u32x4 v;
            v.x = a0 | (a1 << 16);
            v.y = a2 | (a3 << 16);
            v.z = a4 | (a5 << 16);
            v.w = a6 | (a7 << 16);
            unsigned int* dstw = (unsigned int*)nxtHi + widx;
            asm volatile("global_store_dwordx4 %0, %1, off sc0 sc1"
                         :: "v"(dstw), "v"(v) : "memory");
        }

        // ---- release: drain h (+ rare fhT) stores, then arrive ----
        asm volatile("s_waitcnt vmcnt(0)" ::: "memory");
        __syncthreads();   // S3: all of this block's stores acked at the LLC
        const unsigned tgt = (unsigned)(t + 1);
        if (tid == 0) {
            unsigned old = __hip_atomic_fetch_add(&done[0], 1u,
                             __ATOMIC_RELAXED, __HIP_MEMORY_SCOPE_AGENT);
            if (old == tgt * (unsigned)NB - 1u) {
#pragma unroll
                for (int wg = 0; wg < 8; ++wg)
                    __hip_atomic_store(&done[32 + wg * 32], tgt,
                                       __ATOMIC_RELAXED, __HIP_MEMORY_SCOPE_AGENT);
            }
        }
        // ---- per-wave go poll (1 coalesced request per iteration) ----
        {
            const unsigned int* goP = &done[32 + wv * 32];
            while (__hip_atomic_load(goP, __ATOMIC_RELAXED,
                                     __HIP_MEMORY_SCOPE_AGENT) < tgt) {
                __builtin_amdgcn_s_sleep(4);
            }
        }
        __builtin_amdgcn_sched_barrier(0);   // no hoisting of next-step loads

        unsigned short* s;
        s = curHi; curHi = nxtHi; nxtHi = s;
    }
}

// ---------------------------------------------------------------------------
// Kernel C1: denseT[d][b] = relu(fh[b] . dense_w[:,d] + db[d])
__global__ __launch_bounds__(256) void dense_kernel(
    const float* __restrict__ fhT, const float* __restrict__ Wdf,
    const float* __restrict__ dbf, float* __restrict__ denseT)
{
    const int tid  = threadIdx.x;
    const int lane = tid & 63;
    const int wv   = __builtin_amdgcn_readfirstlane(tid >> 6);
    const int d0   = blockIdx.x * 16 + wv * 4;

    float acc[4] = {0.f, 0.f, 0.f, 0.f};
#pragma unroll 4
    for (int k = 0; k < H_; ++k) {
        float v = fhT[k * 64 + lane];
        const float* wr = Wdf + (long)k * D_ + d0;
        acc[0] += wr[0] * v;
        acc[1] += wr[1] * v;
        acc[2] += wr[2] * v;
        acc[3] += wr[3] * v;
    }
#pragma unroll
    for (int c = 0; c < 4; ++c) {
        float z = acc[c] + dbf[d0 + c];
        z = z > 0.f ? z : 0.f;
        denseT[(d0 + c) * 64 + lane] = z;
    }
}

// Kernel C2: logits; output dtype follows detected input dtype.
__global__ void logits_kernel(const float* __restrict__ denseT,
                              const float* __restrict__ Wpf,
                              const float* __restrict__ pbf,
                              const int* __restrict__ flag,
                              void* __restrict__ out)
{
    const int tid  = threadIdx.x;      // 128 threads: 2 waves
    const int lane = tid & 63;
    const int c    = __builtin_amdgcn_readfirstlane(tid >> 6);
    float acc = 0.f;
#pragma unroll 4
    for (int k = 0; k < D_; ++k)
        acc += denseT[k * 64 + lane] * Wpf[k * C_ + c];
    const float r = acc + pbf[c];
    if (*flag != 0) ((float*)out)[lane * C_ + c] = r;
    else            ((unsigned short*)out)[lane * C_ + c] = f2bf(r);
}

// ---------------------------------------------------------------------------
extern "C" void kernel_launch(void* const* d_in, const int* in_sizes, int n_in,
                              void* d_out, int out_size, void* d_ws, size_t ws_size,
                              hipStream_t stream)
{
    // Map inputs by unique flat element counts; fall back to positional.
    const int want[9] = {16384, 64, 25600000, 6291456, 4096, 524288, 512, 1024, 2};
    const void* p[9];
    for (int i = 0; i < 9; ++i) p[i] = d_in[i];
    if (n_in == 9) {
        bool ok = true;
        const void* q[9];
        for (int i = 0; i < 9; ++i) {
            int found = -1;
            for (int j = 0; j < 9; ++j) if (in_sizes[j] == want[i]) { found = j; break; }
            if (found < 0) { ok = false; break; }
            q[i] = d_in[found];
        }
        if (ok) for (int i = 0; i < 9; ++i) p[i] = q[i];
    }
    const int*  X      = (const int*)p[0];
    const int*  seqlen = (const int*)p[1];
    const void* emb    = p[2];
    const void* lk     = p[3];
    const void* lb     = p[4];
    const void* dw     = p[5];
    const void* dbm    = p[6];
    const void* pw     = p[7];
    const void* pbm    = p[8];

    float* w = (float*)d_ws;
    unsigned int* done = (unsigned int*)(w + OFF_BAR);
    int*          flag = (int*)done + 400;   // outside zeroed [0,384) range

    detect_kernel<<<1, 256, 0, stream>>>((const unsigned short*)emb, flag);

    prep_kernel<<<(PREP_TOTAL + 255) / 256, 256, 0, stream>>>(
        lk, lb, dw, dbm, pw, pbm, flag, w);

    xproj_kernel<<<dim3(256, 64), 512, 0, stream>>>(
        X, emb, flag,
        (const unsigned short*)(w + OFF_WBX), w + OFF_BIAS,
        w + OFF_XPROJ);

    lstm_persistent<<<NB, 512, 0, stream>>>((unsigned short*)(w + OFF_HH),
                                            w + OFF_FH,
                                            (const unsigned short*)(w + OFF_WB),
                                            w + OFF_XPROJ,
                                            seqlen, done);

    dense_kernel<<<32, 256, 0, stream>>>(w + OFF_FH, w + OFF_WD,
                                         w + OFF_DB, w + OFF_DEN);
    logits_kernel<<<1, 128, 0, stream>>>(w + OFF_DEN, w + OFF_WP,
                                         w + OFF_PB, flag, d_out);
}

// Round 9
// 2158.170 us; speedup vs baseline: 1.5917x; 1.2405x over previous
//
#include <hip/hip_runtime.h>
#include <hip/hip_bf16.h>

// Problem dims
#define B_   64
#define S_   256
#define E_   512
#define H_   1024
#define D_   512
#define C_   2
#define G4   4096   // 4*H
#define NB   128    // blocks in persistent recurrence

typedef __attribute__((ext_vector_type(8))) short short8;   // 8 bf16 (4 VGPRs)
typedef __attribute__((ext_vector_type(4))) float f32x4;
typedef __attribute__((ext_vector_type(4))) unsigned int u32x4;  // asm-safe 16B

__device__ __forceinline__ float bf2f(unsigned short u) {
    unsigned int x = ((unsigned int)u) << 16;
    return __uint_as_float(x);
}
__device__ __forceinline__ unsigned short f2bf(float f) {
    unsigned int x = __float_as_uint(f);
    unsigned int r = (x + 0x7fffu + ((x >> 16) & 1u)) >> 16;
    return (unsigned short)r;
}

// ---------------------------------------------------------------------------
// Kernel D: detect fp32 (flag=1) vs bf16 (flag=0) float inputs (probe emb).
__global__ void detect_kernel(const unsigned short* __restrict__ emb_u,
                              int* __restrict__ flag)
{
    __shared__ int cnt;
    if (threadIdx.x == 0) cnt = 0;
    __syncthreads();
    int bad = 0;
#pragma unroll
    for (int i = 0; i < 8; ++i) {
        unsigned short u = emb_u[threadIdx.x * 8 + i];
        float a = fabsf(bf2f(u));
        if (!(a < 4.0f)) bad = 1;
        else if (a != 0.0f && a < 1e-20f) bad = 1;
    }
    if (bad) atomicAdd(&cnt, 1);
    __syncthreads();
    if (threadIdx.x == 0) *flag = (cnt > 16) ? 1 : 0;
}

// ---------------------------------------------------------------------------
// Workspace float offsets
#define OFF_WBX   0L          // 2097152 floats = 4M ushorts: x-weight B-frags
                              //   WBX[nt(256)][ks(16)][term][lane][8] (hi,lo)
#define OFF_WB    2097152L    // 4194304 floats = 8.4M ushort: recurrent B-frags
#define OFF_BIAS  6291456L    // 4096
#define OFF_WD    6295552L    // 524288
#define OFF_DB    6819840L    // 512
#define OFF_WP    6820352L    // 1024
#define OFF_PB    6821376L    // 16 (2 used)
#define OFF_FH    6821392L    // 65536
#define OFF_DEN   6886928L    // 32768
#define OFF_HH    6919696L    // h state: 2 ushort bufs of 65536 (hiA, hiB);
                              //   h is SINGLE bf16 (lo residual dropped, r7)
#define OFF_BAR   7050768L    // 512 uints: ctr@0, go@32+w*32 (w=0..7), flag@400
#define OFF_XPROJ 7051280L    // 67108864

// Kernel P: build WBX (x-weight frags) + WB (recurrent frags), copy bias/
// dense/pred params, zero fhT, t=0 h buffers, ctr/go flags.
#define PREP_TOTAL 6952834
__global__ void prep_kernel(const void* __restrict__ lk,
                            const void* __restrict__ lb,
                            const void* __restrict__ dw,
                            const void* __restrict__ dbm,
                            const void* __restrict__ pw,
                            const void* __restrict__ pbm,
                            const int* __restrict__ flag,
                            float* __restrict__ w)
{
    const bool f32 = (*flag != 0);
    long i = (long)blockIdx.x * 256 + threadIdx.x;
    if (i >= PREP_TOTAL) return;
#define CV(p, j) (f32 ? ((const float*)(p))[j] : bf2f(((const unsigned short*)(p))[j]))
    if (i < 2097152) {
        // WBX frag build: item = [nt(256)][ks(16)][lane(64)][j(8)],
        // writes hi (term0) and lo (term1). Source: lk rows 0..511 (x part),
        //   k = ks*32 + (l>>4)*8 + j, n = nt*16 + (l&15).
        int j  = (int)(i & 7);
        int l  = (int)((i >> 3) & 63);
        int ks = (int)((i >> 9) & 15);
        int nt = (int)(i >> 13);
        int k  = ks * 32 + (l >> 4) * 8 + j;
        int n  = nt * 16 + (l & 15);
        long src = (long)k * G4 + n;
        float v = CV(lk, src);
        unsigned short hi = f2bf(v);
        unsigned short lo = f2bf(v - bf2f(hi));
        unsigned short* WBXu = (unsigned short*)(w + OFF_WBX);
        long base = ((long)(nt * 16 + ks) * 2) * 512 + l * 8 + j;
        WBXu[base]       = hi;   // term 0
        WBXu[base + 512] = lo;   // term 1
        return;
    }  i -= 2097152;
    if (i < 4194304) {
        // Recurrent B-frag relayout (unchanged from prior rounds).
        int j  = (int)(i & 7);
        int l  = (int)((i >> 3) & 63);
        int ks = (int)((i >> 9) & 31);
        int bk = (int)(i >> 14);
        int c  = l & 15, q = l >> 4;
        int k  = ks * 32 + q * 8 + j;
        int g  = c >> 2, jj = c & 3;
        long src = (long)(512 + k) * G4 + g * H_ + bk * 4 + jj;
        float v = CV(lk, src);
        unsigned short hi = f2bf(v);
        unsigned short lo = f2bf(v - bf2f(hi));
        unsigned short* WBu = (unsigned short*)(w + OFF_WB);
        long base = ((long)(bk * 32 + ks) * 2) * 512 + l * 8 + j;
        WBu[base]       = hi;   // term 0
        WBu[base + 512] = lo;   // term 1
        return;
    }  i -= 4194304;
    if (i < 4096)    { w[OFF_BIAS + i] = CV(lb, i);  return; }  i -= 4096;
    if (i < 524288)  { w[OFF_WD + i]   = CV(dw, i);  return; }  i -= 524288;
    if (i < 512)     { w[OFF_DB + i]   = CV(dbm, i); return; }  i -= 512;
    if (i < 1024)    { w[OFF_WP + i]   = CV(pw, i);  return; }  i -= 1024;
    if (i < 2)       { w[OFF_PB + i]   = CV(pbm, i); return; }  i -= 2;
    if (i < 65536)   { w[OFF_FH + i] = 0.f; return; }  i -= 65536;
    if (i < 65536)   { ((unsigned int*)(w + OFF_HH))[i] = 0u; return; }  i -= 65536;
    if (i < 384)     { ((unsigned int*)(w + OFF_BAR))[i] = 0u; return; }
#undef CV
}

// ---------------------------------------------------------------------------
// Kernel A v3 (MFMA, B-read-once): xprojT[t][n][b] = emb[X[b,t]] @ Wx + bias
// Grid (t=256, cb=16) x 512 thr. Each wave owns TWO N-tiles (nt = cb*16 +
// wv*2 + ta) and loops over ALL 4 m-tiles with A from LDS -> every WBX line
// is loaded exactly once per block (16 GB -> 2 GB L2 traffic vs v2, which
// re-read each line 4x across waves and ran 64 blocks/t).
// A-frags staged once per block (128 KB LDS). Output layout unchanged.
__global__ __launch_bounds__(512) void xproj_kernel(
    const int* __restrict__ X,
    const void* __restrict__ emb,
    const int* __restrict__ flag,
    const unsigned short* __restrict__ WBXu,
    const float* __restrict__ biasf,
    float* __restrict__ xprojT)
{
    const int t    = blockIdx.x;
    const int cb   = blockIdx.y;        // 0..15 (256 cols each)
    const int tid  = threadIdx.x;
    const int lane = tid & 63;
    const int wv   = __builtin_amdgcn_readfirstlane(tid >> 6);  // 0..7
    const bool f32 = (*flag != 0);

    __shared__ unsigned short Ahi[32768];   // [ks(16)][mt(4)][lane(64)][8]
    __shared__ unsigned short Alo[32768];
    __shared__ int rowid[64];

    if (tid < 64) rowid[tid] = X[tid * S_ + t];
    __syncthreads();

    // ---- stage emb rows -> A-frags (hi/lo bf16), once per block ----
    {
        const int b   = tid >> 3;       // row 0..63
        const int e0  = (tid & 7) * 64; // 64 elems per thread
        const long rb = (long)rowid[b] * E_;
        const int mtb = b >> 4, b15 = b & 15;
        if (f32) {
            const float* src = (const float*)emb + rb + e0;
#pragma unroll
            for (int u = 0; u < 8; ++u) {
                const int e  = e0 + u * 8;
                const int ks = e >> 5;
                const int lf = ((e >> 3) & 3) * 16 + b15;
                const int base = ((ks * 4 + mtb) * 64 + lf) * 8;
                union { unsigned short s[8]; short8 v; } h, l;
#pragma unroll
                for (int k2 = 0; k2 < 8; ++k2) {
                    float v = src[u * 8 + k2];
                    unsigned short hb = f2bf(v);
                    h.s[k2] = hb;
                    l.s[k2] = f2bf(v - bf2f(hb));
                }
                *(short8*)(Ahi + base) = h.v;
                *(short8*)(Alo + base) = l.v;
            }
        } else {
            const unsigned short* src = (const unsigned short*)emb + rb + e0;
            const short8 z = {0, 0, 0, 0, 0, 0, 0, 0};
#pragma unroll
            for (int u = 0; u < 8; ++u) {
                const int e  = e0 + u * 8;
                const int ks = e >> 5;
                const int lf = ((e >> 3) & 3) * 16 + b15;
                const int base = ((ks * 4 + mtb) * 64 + lf) * 8;
                *(short8*)(Ahi + base) = *(const short8*)(src + u * 8);
                *(short8*)(Alo + base) = z;
            }
        }
    }
    __syncthreads();

    // ---- MFMA: 16 ks x {load B once} x 4 mt x 2 tiles x 3 terms ----
    f32x4 acc[4][2];
#pragma unroll
    for (int m = 0; m < 4; ++m)
#pragma unroll
        for (int ta = 0; ta < 2; ++ta) acc[m][ta] = {0.f, 0.f, 0.f, 0.f};

    const int nt0 = cb * 16 + wv * 2;
#pragma unroll
    for (int ks = 0; ks < 16; ++ks) {
        short8 bhi[2], blo[2];
#pragma unroll
        for (int ta = 0; ta < 2; ++ta) {
            const long wb = ((long)((nt0 + ta) * 16 + ks) * 2) * 512 + lane * 8;
            bhi[ta] = *(const short8*)(WBXu + wb);
            blo[ta] = *(const short8*)(WBXu + wb + 512);
        }
#pragma unroll
        for (int m = 0; m < 4; ++m) {
            short8 ahi = *(const short8*)(Ahi + ((ks * 4 + m) * 64 + lane) * 8);
            short8 alo = *(const short8*)(Alo + ((ks * 4 + m) * 64 + lane) * 8);
#pragma unroll
            for (int ta = 0; ta < 2; ++ta) {
                acc[m][ta] = __builtin_amdgcn_mfma_f32_16x16x32_bf16(ahi, bhi[ta], acc[m][ta], 0, 0, 0);
                acc[m][ta] = __builtin_amdgcn_mfma_f32_16x16x32_bf16(ahi, blo[ta], acc[m][ta], 0, 0, 0);
                acc[m][ta] = __builtin_amdgcn_mfma_f32_16x16x32_bf16(alo, bhi[ta], acc[m][ta], 0, 0, 0);
            }
        }
    }

    // ---- epilogue: bias + store (C layout: col=lane&15, row=(lane>>4)*4+r) ----
    const int col = lane & 15, rg = lane >> 4;
#pragma unroll
    for (int ta = 0; ta < 2; ++ta) {
        const int n = (nt0 + ta) * 16 + col;
        const float bz = biasf[n];
        float* dst = xprojT + ((long)t * G4 + n) * 64;
#pragma unroll
        for (int m = 0; m < 4; ++m) {
            float4 o;
            o.x = acc[m][ta][0] + bz;
            o.y = acc[m][ta][1] + bz;
            o.z = acc[m][ta][2] + bz;
            o.w = acc[m][ta][3] + bz;
            *(float4*)(dst + m * 16 + rg * 4) = o;
        }
    }
}

// ---------------------------------------------------------------------------
// Persistent MFMA LSTM recurrence (round 7, unchanged). 128 blocks x 512 thr.
// FENCELESS LLC protocol; h single bf16; atomicAdd-last-arriver barrier.
__global__ __launch_bounds__(512, 2) void lstm_persistent(
    unsigned short* __restrict__ hU,     // hiA | hiB (65536 ushorts each)
    float* __restrict__ fhT,
    const unsigned short* __restrict__ WBg,
    const float* __restrict__ xprojT,
    const int* __restrict__ seqlen, unsigned int* __restrict__ done)
{
    const int tid  = threadIdx.x;
    const int lane = tid & 63;
    const int wv   = __builtin_amdgcn_readfirstlane(tid >> 6);  // 0..7
    const int bk   = blockIdx.x;        // 0..127
    const int mt   = wv & 3;            // m-tile (batch rows mt*16..+15)
    const int kh   = wv >> 2;           // k-half (ks in [kh*16, kh*16+16))

    __shared__ unsigned short WBl[65536];   // 128 KB B-frags (2 tiles)
    __shared__ float gates[2][64][33];      // [kh][m][tile*16+c] partials
    __shared__ float cTl[512];              // [jj][b] cell state
    __shared__ unsigned short hEx[512];     // [jj*64+b] h exchange (bf16)

    // stage weight frags (once) + init c
    {
        const uint4* src = (const uint4*)(WBg + (long)bk * 65536);
        uint4* dst = (uint4*)WBl;
#pragma unroll
        for (int u = 0; u < 16; ++u) dst[tid + u * 512] = src[tid + u * 512];
        cTl[tid] = 0.f;
    }
    __syncthreads();

    const int myseq = seqlen[lane];
    const int q = lane >> 4, c = lane & 15;
    const int jj = wv;                  // pointwise j owner: j = bk*8 + jj

    unsigned short* hiA = hU;
    unsigned short* hiB = hU + 65536;
    unsigned short *curHi = hiA, *nxtHi = hiB;

    const int bb  = tid & 63;
    const long widx = (long)(bk >> 2) * 1024 + (bb >> 4) * 256
                    + (bk & 3) * 64 + (bb & 15) * 4;

    const long xoff = (long)(bk * 8 + jj);

    for (int t = 0; t < S_; ++t) {
        // ---- A-frag loads: m-tile mt, k-half kh; 16 x 16B, LLC-coherent ----
        const unsigned short* hiP = curHi + ((long)mt * 64 + lane) * 8;
        const int ks0 = kh * 16;

        u32x4 hb[16];
#pragma unroll
        for (int u = 0; u < 16; ++u) {
            asm volatile("global_load_dwordx4 %0, %1, off sc0 sc1"
                         : "=v"(hb[u])
                         : "v"(hiP + (long)(ks0 + u) * 2048) : "memory");
        }
        // xproj loads issued AFTER the h loads (drained by S1 under MFMA)
        float xq0, xq1, xq2, xq3;
        {
            const long xb = (long)t * G4 + xoff;
            const float* x0 = xprojT + (xb + 0 * H_) * 64 + lane;
            const float* x1 = xprojT + (xb + 1 * H_) * 64 + lane;
            const float* x2 = xprojT + (xb + 2 * H_) * 64 + lane;
            const float* x3 = xprojT + (xb + 3 * H_) * 64 + lane;
            asm volatile("global_load_dword %0, %1, off" : "=v"(xq0) : "v"(x0) : "memory");
            asm volatile("global_load_dword %0, %1, off" : "=v"(xq1) : "v"(x1) : "memory");
            asm volatile("global_load_dword %0, %1, off" : "=v"(xq2) : "v"(x2) : "memory");
            asm volatile("global_load_dword %0, %1, off" : "=v"(xq3) : "v"(x3) : "memory");
        }
        // wait for the 16 h loads only (4 xproj still outstanding)
        asm volatile("s_waitcnt vmcnt(4)" ::: "memory");
        __builtin_amdgcn_sched_barrier(0);

        f32x4 acc[2][2];
#pragma unroll
        for (int ta = 0; ta < 2; ++ta)
#pragma unroll
            for (int tm = 0; tm < 2; ++tm) acc[ta][tm] = {0.f, 0.f, 0.f, 0.f};

#pragma unroll
        for (int u = 0; u < 16; ++u) {
            short8 ahi = __builtin_bit_cast(short8, hb[u]);
            const int ks = ks0 + u;
#pragma unroll
            for (int ta = 0; ta < 2; ++ta) {
                short8 bhi = *(const short8*)(&WBl[ta * 32768 + (ks * 2 + 0) * 512 + (lane << 3)]);
                short8 blo = *(const short8*)(&WBl[ta * 32768 + (ks * 2 + 1) * 512 + (lane << 3)]);
                acc[ta][0] = __builtin_amdgcn_mfma_f32_16x16x32_bf16(ahi, bhi, acc[ta][0], 0, 0, 0);
                acc[ta][1] = __builtin_amdgcn_mfma_f32_16x16x32_bf16(ahi, blo, acc[ta][1], 0, 0, 0);
            }
        }

        // C tile -> LDS partials: lane (q,c), reg r = C[m=mt*16+q*4+r][tile c]
#pragma unroll
        for (int ta = 0; ta < 2; ++ta)
#pragma unroll
            for (int r = 0; r < 4; ++r)
                gates[kh][mt * 16 + q * 4 + r][ta * 16 + c] =
                    acc[ta][0][r] + acc[ta][1][r];
        __syncthreads();   // S1 (also drains the xproj loads)

        asm volatile("s_waitcnt vmcnt(0)" ::: "memory");  // xq ready (usually free)
        __builtin_amdgcn_sched_barrier(0);

        // pointwise: thread (jj, b=lane); gate g at block-col g*8+jj
        //   -> tile (jj>>2), tile-col g*4+(jj&3); gate order i,j,f,o
        {
            const int b  = lane;
            const int tb = (jj >> 2) * 16 + (jj & 3);
            const float gi = gates[0][b][tb +  0] + gates[1][b][tb +  0] + xq0;
            const float gj = gates[0][b][tb +  4] + gates[1][b][tb +  4] + xq1;
            const float gf = gates[0][b][tb +  8] + gates[1][b][tb +  8] + xq2;
            const float go = gates[0][b][tb + 12] + gates[1][b][tb + 12] + xq3;

            const float c_old = cTl[jj * 64 + b];
            const float fgate = 1.f / (1.f + expf(-(gf + 1.0f)));  // forget bias
            const float igate = 1.f / (1.f + expf(-gi));
            const float ogate = 1.f / (1.f + expf(-go));
            const float cnew  = c_old * fgate + igate * tanhf(gj);
            const float hnew  = tanhf(cnew) * ogate;
            cTl[jj * 64 + b] = cnew;

            hEx[jj * 64 + b] = f2bf(hnew);
            if (t == myseq - 1) fhT[(bk * 8 + jj) * 64 + b] = hnew;
        }
        __syncthreads();   // S2

        // ---- packed 16B h store (write-through to LLC), wave 0 only ----
        if (tid < 64) {
            unsigned a0 = hEx[0 * 64 + bb], a1 = hEx[1 * 64 + bb];
            unsigned a2 = hEx[2 * 64 + bb], a3 = hEx[3 * 64 + bb];
            unsigned a4 = hEx[4 * 64 + bb], a5 = hEx[5 * 64 + bb];
            unsigned a6 = hEx[6 * 64 + bb], a7 = hEx[7 * 64 + bb];
            u32x4 v;
            v.x = a0 | (a1 << 16);
            v.y = a2 | (a3 << 16);
            v.z = a4 | (a5 << 16);
            v.w = a6 | (a7 << 16);
            unsigned int* dstw = (unsigned int*)nxtHi + widx;
            asm volatile("global_store_dwordx4 %0, %1, off sc0 sc1"
                         :: "v"(dstw), "v"(v) : "memory");
        }

        // ---- release: drain h (+ rare fhT) stores, then arrive ----
        asm volatile("s_waitcnt vmcnt(0)" ::: "memory");
        __syncthreads();   // S3: all of this block's stores acked at the LLC
        const unsigned tgt = (unsigned)(t + 1);
        if (tid == 0) {
            unsigned old = __hip_atomic_fetch_add(&done[0], 1u,
                             __ATOMIC_RELAXED, __HIP_MEMORY_SCOPE_AGENT);
            if (old == tgt * (unsigned)NB - 1u) {
#pragma unroll
                for (int wg = 0; wg < 8; ++wg)
                    __hip_atomic_store(&done[32 + wg * 32], tgt,
                                       __ATOMIC_RELAXED, __HIP_MEMORY_SCOPE_AGENT);
            }
        }
        // ---- per-wave go poll (1 coalesced request per iteration) ----
        {
            const unsigned int* goP = &done[32 + wv * 32];
            while (__hip_atomic_load(goP, __ATOMIC_RELAXED,
                                     __HIP_MEMORY_SCOPE_AGENT) < tgt) {
                __builtin_amdgcn_s_sleep(4);
            }
        }
        __builtin_amdgcn_sched_barrier(0);   // no hoisting of next-step loads

        unsigned short* s;
        s = curHi; curHi = nxtHi; nxtHi = s;
    }
}

// ---------------------------------------------------------------------------
// Kernel C1: denseT[d][b] = relu(fh[b] . dense_w[:,d] + db[d])
__global__ __launch_bounds__(256) void dense_kernel(
    const float* __restrict__ fhT, const float* __restrict__ Wdf,
    const float* __restrict__ dbf, float* __restrict__ denseT)
{
    const int tid  = threadIdx.x;
    const int lane = tid & 63;
    const int wv   = __builtin_amdgcn_readfirstlane(tid >> 6);
    const int d0   = blockIdx.x * 16 + wv * 4;

    float acc[4] = {0.f, 0.f, 0.f, 0.f};
#pragma unroll 4
    for (int k = 0; k < H_; ++k) {
        float v = fhT[k * 64 + lane];
        const float* wr = Wdf + (long)k * D_ + d0;
        acc[0] += wr[0] * v;
        acc[1] += wr[1] * v;
        acc[2] += wr[2] * v;
        acc[3] += wr[3] * v;
    }
#pragma unroll
    for (int c = 0; c < 4; ++c) {
        float z = acc[c] + dbf[d0 + c];
        z = z > 0.f ? z : 0.f;
        denseT[(d0 + c) * 64 + lane] = z;
    }
}

// Kernel C2: logits; output dtype follows detected input dtype.
__global__ void logits_kernel(const float* __restrict__ denseT,
                              const float* __restrict__ Wpf,
                              const float* __restrict__ pbf,
                              const int* __restrict__ flag,
                              void* __restrict__ out)
{
    const int tid  = threadIdx.x;      // 128 threads: 2 waves
    const int lane = tid & 63;
    const int c    = __builtin_amdgcn_readfirstlane(tid >> 6);
    float acc = 0.f;
#pragma unroll 4
    for (int k = 0; k < D_; ++k)
        acc += denseT[k * 64 + lane] * Wpf[k * C_ + c];
    const float r = acc + pbf[c];
    if (*flag != 0) ((float*)out)[lane * C_ + c] = r;
    else            ((unsigned short*)out)[lane * C_ + c] = f2bf(r);
}

// ---------------------------------------------------------------------------
extern "C" void kernel_launch(void* const* d_in, const int* in_sizes, int n_in,
                              void* d_out, int out_size, void* d_ws, size_t ws_size,
                              hipStream_t stream)
{
    // Map inputs by unique flat element counts; fall back to positional.
    const int want[9] = {16384, 64, 25600000, 6291456, 4096, 524288, 512, 1024, 2};
    const void* p[9];
    for (int i = 0; i < 9; ++i) p[i] = d_in[i];
    if (n_in == 9) {
        bool ok = true;
        const void* q[9];
        for (int i = 0; i < 9; ++i) {
            int found = -1;
            for (int j = 0; j < 9; ++j) if (in_sizes[j] == want[i]) { found = j; break; }
            if (found < 0) { ok = false; break; }
            q[i] = d_in[found];
        }
        if (ok) for (int i = 0; i < 9; ++i) p[i] = q[i];
    }
    const int*  X      = (const int*)p[0];
    const int*  seqlen = (const int*)p[1];
    const void* emb    = p[2];
    const void* lk     = p[3];
    const void* lb     = p[4];
    const void* dw     = p[5];
    const void* dbm    = p[6];
    const void* pw     = p[7];
    const void* pbm    = p[8];

    float* w = (float*)d_ws;
    unsigned int* done = (unsigned int*)(w + OFF_BAR);
    int*          flag = (int*)done + 400;   // outside zeroed [0,384) range

    detect_kernel<<<1, 256, 0, stream>>>((const unsigned short*)emb, flag);

    prep_kernel<<<(PREP_TOTAL + 255) / 256, 256, 0, stream>>>(
        lk, lb, dw, dbm, pw, pbm, flag, w);

    xproj_kernel<<<dim3(256, 16), 512, 0, stream>>>(
        X, emb, flag,
        (const unsigned short*)(w + OFF_WBX), w + OFF_BIAS,
        w + OFF_XPROJ);

    lstm_persistent<<<NB, 512, 0, stream>>>((unsigned short*)(w + OFF_HH),
                                            w + OFF_FH,
                                            (const unsigned short*)(w + OFF_WB),
                                            w + OFF_XPROJ,
                                            seqlen, done);

    dense_kernel<<<32, 256, 0, stream>>>(w + OFF_FH, w + OFF_WD,
                                         w + OFF_DB, w + OFF_DEN);
    logits_kernel<<<1, 128, 0, stream>>>(w + OFF_DEN, w + OFF_WP,
                                         w + OFF_PB, flag, d_out);
}